// Round 1
// baseline (915.035 us; speedup 1.0000x reference)
//
#include <hip/hip_runtime.h>
#include <hip/hip_bf16.h>

#define OC_N     2048
#define IC_N     2048
#define RC       6144      // rows = OC_N*3, cols = IC_N*3
#define OCSTRIDE 18432     // IC_N*9 floats per oc slice

__device__ __forceinline__ float wave_reduce(float x) {
#pragma unroll
    for (int off = 32; off > 0; off >>= 1) x += __shfl_down(x, off, 64);
    return x;
}

// v[oc*3+hh] = rsqrt(sum(u^2)) * sum_{ic,ww} conv[oc][ic][hh][ww] * u[ic*3+ww]
// one block per oc, 256 threads
__global__ __launch_bounds__(256) void vstep_kernel(
    const float* __restrict__ conv, const float* __restrict__ u,
    float* __restrict__ v_out)
{
    __shared__ float u_lds[RC];
    __shared__ float sred[8];
    __shared__ float sred3[12];
    __shared__ float sbcast;

    const int tid  = threadIdx.x;
    const int oc   = blockIdx.x;
    const int lane = tid & 63;
    const int wid  = tid >> 6;

    // stage u into LDS + compute sum of squares
    float sq = 0.f;
    const float4* u4  = reinterpret_cast<const float4*>(u);
    float4*       ul4 = reinterpret_cast<float4*>(u_lds);
#pragma unroll
    for (int k = 0; k < 6; ++k) {              // 6144/4 = 1536 float4 / 256 thr
        float4 q = u4[tid + 256 * k];
        ul4[tid + 256 * k] = q;
        sq += q.x * q.x + q.y * q.y + q.z * q.z + q.w * q.w;
    }
    float wsum = wave_reduce(sq);
    if (lane == 0) sred[wid] = wsum;
    __syncthreads();
    if (tid == 0) sbcast = rsqrtf(sred[0] + sred[1] + sred[2] + sred[3]);
    __syncthreads();
    const float scale = sbcast;

    float acc0 = 0.f, acc1 = 0.f, acc2 = 0.f;
    const float* base = conv + (size_t)oc * OCSTRIDE;
#pragma unroll
    for (int gi = 0; gi < 2; ++gi) {
        const int g = tid + 256 * gi;          // ic-group of 4: ic = 4g..4g+3
        const float4* p4  = reinterpret_cast<const float4*>(base + g * 36);
        const float4* q12 = reinterpret_cast<const float4*>(u_lds + 12 * g);
        float uv[12];
#pragma unroll
        for (int k = 0; k < 3; ++k) {
            float4 q = q12[k];
            uv[4 * k] = q.x; uv[4 * k + 1] = q.y; uv[4 * k + 2] = q.z; uv[4 * k + 3] = q.w;
        }
#pragma unroll
        for (int j = 0; j < 9; ++j) {
            float4 q = p4[j];
            float el[4] = {q.x, q.y, q.z, q.w};
#pragma unroll
            for (int e = 0; e < 4; ++e) {
                const int m   = 4 * j + e;     // element in 36-group (compile-time)
                const int icl = m / 9;
                const int rem = m - 9 * icl;
                const int hh  = rem / 3;
                const int ww  = rem - 3 * hh;
                const float pv = el[e] * uv[icl * 3 + ww];
                if (hh == 0) acc0 += pv;
                else if (hh == 1) acc1 += pv;
                else acc2 += pv;
            }
        }
    }
    acc0 = wave_reduce(acc0);
    acc1 = wave_reduce(acc1);
    acc2 = wave_reduce(acc2);
    if (lane == 0) { sred3[wid] = acc0; sred3[4 + wid] = acc1; sred3[8 + wid] = acc2; }
    __syncthreads();
    if (tid < 3) {
        const float s = sred3[tid * 4 + 0] + sred3[tid * 4 + 1] +
                        sred3[tid * 4 + 2] + sred3[tid * 4 + 3];
        // note: sred3 layout is [hh*4+wid] -> rewrite index below
        v_out[oc * 3 + tid] = scale * s;
    }
}

// partials[b][ic*3+ww] = sum_{oc in block b's 8, hh} conv[oc][ic][hh][ww] * v_n[oc*3+hh]
// 256 blocks x 256 threads, block b handles oc in [8b, 8b+8)
__global__ __launch_bounds__(256) void ustep_kernel(
    const float* __restrict__ conv, const float* __restrict__ v,
    float* __restrict__ partials)
{
    __shared__ float v_lds[24];
    __shared__ float sred[8];
    __shared__ float sbcast;

    const int tid  = threadIdx.x;
    const int b    = blockIdx.x;
    const int lane = tid & 63;
    const int wid  = tid >> 6;

    // sum of squares of full v (6144), coalesced
    float sq = 0.f;
#pragma unroll
    for (int k = 0; k < 24; ++k) {
        float x = v[tid + 256 * k];
        sq += x * x;
    }
    float wsum = wave_reduce(sq);
    if (lane == 0) sred[wid] = wsum;
    __syncthreads();
    if (tid == 0) sbcast = rsqrtf(sred[0] + sred[1] + sred[2] + sred[3]);
    __syncthreads();
    if (tid < 24) v_lds[tid] = v[b * 24 + tid] * sbcast;
    __syncthreads();

    float acc[24];
#pragma unroll
    for (int i = 0; i < 24; ++i) acc[i] = 0.f;

    for (int ocl = 0; ocl < 8; ++ocl) {
        const int oc = b * 8 + ocl;
        const float vs0 = v_lds[ocl * 3 + 0];
        const float vs1 = v_lds[ocl * 3 + 1];
        const float vs2 = v_lds[ocl * 3 + 2];
        const float* base = conv + (size_t)oc * OCSTRIDE;
#pragma unroll
        for (int gi = 0; gi < 2; ++gi) {
            const int g = tid + 256 * gi;
            const float4* p4 = reinterpret_cast<const float4*>(base + g * 36);
#pragma unroll
            for (int j = 0; j < 9; ++j) {
                float4 q = p4[j];
                float el[4] = {q.x, q.y, q.z, q.w};
#pragma unroll
                for (int e = 0; e < 4; ++e) {
                    const int m   = 4 * j + e;
                    const int icl = m / 9;
                    const int rem = m - 9 * icl;
                    const int hh  = rem / 3;
                    const int ww  = rem - 3 * hh;
                    const float vv = (hh == 0) ? vs0 : ((hh == 1) ? vs1 : vs2);
                    acc[gi * 12 + icl * 3 + ww] += el[e] * vv;
                }
            }
        }
    }

    float* pout = partials + (size_t)b * RC;
#pragma unroll
    for (int gi = 0; gi < 2; ++gi) {
        const int g = tid + 256 * gi;
        float4* o4 = reinterpret_cast<float4*>(pout + 12 * g);
#pragma unroll
        for (int k = 0; k < 3; ++k) {
            o4[k] = make_float4(acc[gi * 12 + 4 * k + 0], acc[gi * 12 + 4 * k + 1],
                                acc[gi * 12 + 4 * k + 2], acc[gi * 12 + 4 * k + 3]);
        }
    }
}

// u_out[s] = sum_b partials[b][s]   (24 blocks x 256 threads = 6144 slots)
__global__ __launch_bounds__(256) void ureduce_kernel(
    const float* __restrict__ partials, float* __restrict__ u_out)
{
    const int s = blockIdx.x * 256 + threadIdx.x;
    float sum = 0.f;
#pragma unroll 8
    for (int b = 0; b < 256; ++b) sum += partials[(size_t)b * RC + s];
    u_out[s] = sum;
}

// out = 3 * rsqrt(sum v^2) * dot(v, t)
__global__ __launch_bounds__(256) void final_kernel(
    const float* __restrict__ v, const float* __restrict__ t,
    float* __restrict__ out)
{
    __shared__ float ssq[4];
    __shared__ float sdot[4];
    const int tid  = threadIdx.x;
    const int lane = tid & 63;
    const int wid  = tid >> 6;
    float sq = 0.f, dot = 0.f;
#pragma unroll
    for (int k = 0; k < 24; ++k) {
        float x = v[tid + 256 * k];
        float y = t[tid + 256 * k];
        sq  += x * x;
        dot += x * y;
    }
    sq  = wave_reduce(sq);
    dot = wave_reduce(dot);
    if (lane == 0) { ssq[wid] = sq; sdot[wid] = dot; }
    __syncthreads();
    if (tid == 0) {
        const float sqt  = ssq[0] + ssq[1] + ssq[2] + ssq[3];
        const float dott = sdot[0] + sdot[1] + sdot[2] + sdot[3];
        out[0] = 3.0f * dott * rsqrtf(sqt);
    }
}

extern "C" void kernel_launch(void* const* d_in, const int* in_sizes, int n_in,
                              void* d_out, int out_size, void* d_ws, size_t ws_size,
                              hipStream_t stream)
{
    const float* conv = (const float*)d_in[0];   // [2048,2048,3,3] fp32
    const float* u_in = (const float*)d_in[1];   // [1,6144] fp32, unit norm
    float* out = (float*)d_out;
    float* ws  = (float*)d_ws;

    // ws layout (floats): v_vec[6144] | u_vec[6144] | t_vec[6144] | partials[256*6144]
    const size_t needed = (size_t)(3 * RC + 256 * RC) * sizeof(float);
    if (ws_size < needed) return;   // fail loudly rather than corrupt memory

    float* v_vec    = ws;
    float* u_vec    = ws + RC;
    float* t_vec    = ws + 2 * RC;
    float* partials = ws + 3 * RC;

    for (int i = 0; i < 10; ++i) {
        vstep_kernel<<<OC_N, 256, 0, stream>>>(conv, (i == 0) ? u_in : u_vec, v_vec);
        ustep_kernel<<<256, 256, 0, stream>>>(conv, v_vec, partials);
        ureduce_kernel<<<24, 256, 0, stream>>>(partials, u_vec);
    }
    vstep_kernel<<<OC_N, 256, 0, stream>>>(conv, u_vec, t_vec);
    final_kernel<<<1, 256, 0, stream>>>(v_vec, t_vec, out);
}

// Round 2
// 586.300 us; speedup vs baseline: 1.5607x; 1.5607x over previous
//
#include <hip/hip_runtime.h>
#include <hip/hip_bf16.h>
#include <hip/hip_fp16.h>

#define OC_N     2048
#define IC_N     2048
#define RC       6144      // rows = OC_N*3, cols = IC_N*3
#define OCSTRIDE 18432     // IC_N*9 floats per oc slice
#define RGROUPS  128       // ustep row-groups
#define RROWS    48        // rows per ustep block (128*48 = 6144)

__device__ __forceinline__ float wave_reduce(float x) {
#pragma unroll
    for (int off = 32; off > 0; off >>= 1) x += __shfl_down(x, off, 64);
    return x;
}

// ---------------------------------------------------------------------------
// Build Wh[r][c] = conv[oc][ic][hh][ww] as row-major fp16, r=oc*3+hh, c=ic*3+ww.
// Output-centric: each thread writes 8 consecutive fp16 (one 16B store,
// coalesced); reads are scattered fp32 but with strong L1 locality.
__global__ __launch_bounds__(256) void convert_kernel(
    const float* __restrict__ conv, __half* __restrict__ Wh)
{
    const int t  = blockIdx.x * 256 + threadIdx.x;   // one thread per 8 outputs
    const int o8 = t * 8;
    const int r  = o8 / RC;
    const int c0 = o8 % RC;
    const int oc = r / 3, hh = r % 3;
    const float* base = conv + (size_t)oc * OCSTRIDE + hh * 3;
    union { uint4 q; __half h[8]; } pk;
#pragma unroll
    for (int e = 0; e < 8; ++e) {
        const int c  = c0 + e;
        const int ic = c / 3, ww = c - 3 * ic;
        pk.h[e] = __float2half(base[ic * 9 + ww]);
    }
    *reinterpret_cast<uint4*>(Wh + (size_t)r * RC + c0) = pk.q;
}

// ---------------------------------------------------------------------------
// v_out[r] = rsqrt(||u||^2) * sum_c Wh[r][c] * u[c]
// grid 384 blocks x 256 thr; block covers 16 rows, wave w handles 4 rows.
__global__ __launch_bounds__(256) void vstep_h_kernel(
    const __half* __restrict__ Wh, const float* __restrict__ u,
    float* __restrict__ v_out)
{
    __shared__ float u_lds[RC];
    __shared__ float sred[4];
    __shared__ float sbcast;
    const int tid = threadIdx.x, lane = tid & 63, wid = tid >> 6;

    // stage u into LDS + sum of squares
    float sq = 0.f;
    const float4* u4  = reinterpret_cast<const float4*>(u);
    float4*       ul4 = reinterpret_cast<float4*>(u_lds);
#pragma unroll
    for (int k = 0; k < 6; ++k) {
        float4 q = u4[tid + 256 * k];
        ul4[tid + 256 * k] = q;
        sq += q.x * q.x + q.y * q.y + q.z * q.z + q.w * q.w;
    }
    sq = wave_reduce(sq);
    if (lane == 0) sred[wid] = sq;
    __syncthreads();
    if (tid == 0) sbcast = rsqrtf(sred[0] + sred[1] + sred[2] + sred[3]);
    __syncthreads();
    const float scale = sbcast;

    const int rbase = blockIdx.x * 16 + wid * 4;
#pragma unroll
    for (int i = 0; i < 4; ++i) {
        const int r = rbase + i;
        const __half* wrow = Wh + (size_t)r * RC;
        float a0=0,a1=0,a2=0,a3=0,a4=0,a5=0,a6=0,a7=0;
#pragma unroll
        for (int it = 0; it < 12; ++it) {
            const int ca = it * 512 + lane * 4;   // 4 fp16 per lane, wave = 512B
            const int cb = ca + 256;
            union { float2 f; __half h[4]; } wa, wb;
            wa.f = *reinterpret_cast<const float2*>(wrow + ca);
            wb.f = *reinterpret_cast<const float2*>(wrow + cb);
            const float4 ua = *reinterpret_cast<const float4*>(u_lds + ca);
            const float4 ub = *reinterpret_cast<const float4*>(u_lds + cb);
            a0 += __half2float(wa.h[0]) * ua.x;
            a1 += __half2float(wa.h[1]) * ua.y;
            a2 += __half2float(wa.h[2]) * ua.z;
            a3 += __half2float(wa.h[3]) * ua.w;
            a4 += __half2float(wb.h[0]) * ub.x;
            a5 += __half2float(wb.h[1]) * ub.y;
            a6 += __half2float(wb.h[2]) * ub.z;
            a7 += __half2float(wb.h[3]) * ub.w;
        }
        float acc = ((a0 + a1) + (a2 + a3)) + ((a4 + a5) + (a6 + a7));
        acc = wave_reduce(acc);
        if (lane == 0) v_out[r] = scale * acc;
    }
}

// ---------------------------------------------------------------------------
// partials[rg][c] = sum_{r in rg's 48 rows} Wh[r][c] * v_n[r]
// grid 384 = 3 col-groups x 128 row-groups; thread owns 8 consecutive cols.
__global__ __launch_bounds__(256) void ustep_h_kernel(
    const __half* __restrict__ Wh, const float* __restrict__ v,
    float* __restrict__ partials)
{
    __shared__ float sred[4];
    __shared__ float sbcast;
    __shared__ float v_lds[RROWS];
    const int tid = threadIdx.x, lane = tid & 63, wid = tid >> 6;
    const int cg = blockIdx.x % 3;
    const int rg = blockIdx.x / 3;

    float sq = 0.f;
#pragma unroll
    for (int k = 0; k < 24; ++k) { float x = v[tid + 256 * k]; sq += x * x; }
    sq = wave_reduce(sq);
    if (lane == 0) sred[wid] = sq;
    __syncthreads();
    if (tid == 0) sbcast = rsqrtf(sred[0] + sred[1] + sred[2] + sred[3]);
    __syncthreads();
    if (tid < RROWS) v_lds[tid] = v[rg * RROWS + tid] * sbcast;
    __syncthreads();

    const int c0 = cg * 2048 + tid * 8;
    float acc[8];
#pragma unroll
    for (int e = 0; e < 8; ++e) acc[e] = 0.f;
    const __half* wp = Wh + (size_t)(rg * RROWS) * RC + c0;
#pragma unroll 4
    for (int rr = 0; rr < RROWS; ++rr) {
        union { uint4 q; __half h[8]; } w8;
        w8.q = *reinterpret_cast<const uint4*>(wp);   // 16B/lane, coalesced
        wp += RC;
        const float vv = v_lds[rr];
#pragma unroll
        for (int e = 0; e < 8; ++e) acc[e] += __half2float(w8.h[e]) * vv;
    }
    float* po = partials + (size_t)rg * RC + c0;
    *reinterpret_cast<float4*>(po)     = make_float4(acc[0], acc[1], acc[2], acc[3]);
    *reinterpret_cast<float4*>(po + 4) = make_float4(acc[4], acc[5], acc[6], acc[7]);
}

// u_out[s] = sum_rg partials[rg][s]   (24 blocks x 256 threads)
__global__ __launch_bounds__(256) void ureduce_kernel(
    const float* __restrict__ partials, float* __restrict__ u_out)
{
    const int s = blockIdx.x * 256 + threadIdx.x;
    float sum = 0.f;
#pragma unroll 8
    for (int b = 0; b < RGROUPS; ++b) sum += partials[(size_t)b * RC + s];
    u_out[s] = sum;
}

// ---------------------------------------------------------------------------
// Final fp32 pass on the ORIGINAL conv data (full precision for sigma):
// t[r] = rsqrt(||u||^2) * sum_c W[r][c]*u[c]   (validated absmax 0.0 in R1)
__global__ __launch_bounds__(256) void vstep_kernel(
    const float* __restrict__ conv, const float* __restrict__ u,
    float* __restrict__ v_out)
{
    __shared__ float u_lds[RC];
    __shared__ float sred[8];
    __shared__ float sred3[12];
    __shared__ float sbcast;

    const int tid  = threadIdx.x;
    const int oc   = blockIdx.x;
    const int lane = tid & 63;
    const int wid  = tid >> 6;

    float sq = 0.f;
    const float4* u4  = reinterpret_cast<const float4*>(u);
    float4*       ul4 = reinterpret_cast<float4*>(u_lds);
#pragma unroll
    for (int k = 0; k < 6; ++k) {
        float4 q = u4[tid + 256 * k];
        ul4[tid + 256 * k] = q;
        sq += q.x * q.x + q.y * q.y + q.z * q.z + q.w * q.w;
    }
    float wsum = wave_reduce(sq);
    if (lane == 0) sred[wid] = wsum;
    __syncthreads();
    if (tid == 0) sbcast = rsqrtf(sred[0] + sred[1] + sred[2] + sred[3]);
    __syncthreads();
    const float scale = sbcast;

    float acc0 = 0.f, acc1 = 0.f, acc2 = 0.f;
    const float* base = conv + (size_t)oc * OCSTRIDE;
#pragma unroll
    for (int gi = 0; gi < 2; ++gi) {
        const int g = tid + 256 * gi;
        const float4* p4  = reinterpret_cast<const float4*>(base + g * 36);
        const float4* q12 = reinterpret_cast<const float4*>(u_lds + 12 * g);
        float uv[12];
#pragma unroll
        for (int k = 0; k < 3; ++k) {
            float4 q = q12[k];
            uv[4 * k] = q.x; uv[4 * k + 1] = q.y; uv[4 * k + 2] = q.z; uv[4 * k + 3] = q.w;
        }
#pragma unroll
        for (int j = 0; j < 9; ++j) {
            float4 q = p4[j];
            float el[4] = {q.x, q.y, q.z, q.w};
#pragma unroll
            for (int e = 0; e < 4; ++e) {
                const int m   = 4 * j + e;
                const int icl = m / 9;
                const int rem = m - 9 * icl;
                const int hh  = rem / 3;
                const int ww  = rem - 3 * hh;
                const float pv = el[e] * uv[icl * 3 + ww];
                if (hh == 0) acc0 += pv;
                else if (hh == 1) acc1 += pv;
                else acc2 += pv;
            }
        }
    }
    acc0 = wave_reduce(acc0);
    acc1 = wave_reduce(acc1);
    acc2 = wave_reduce(acc2);
    if (lane == 0) { sred3[wid] = acc0; sred3[4 + wid] = acc1; sred3[8 + wid] = acc2; }
    __syncthreads();
    if (tid < 3) {
        const float s = sred3[tid * 4 + 0] + sred3[tid * 4 + 1] +
                        sred3[tid * 4 + 2] + sred3[tid * 4 + 3];
        v_out[oc * 3 + tid] = scale * s;
    }
}

// out = 3 * rsqrt(sum v^2) * dot(v, t)
__global__ __launch_bounds__(256) void final_kernel(
    const float* __restrict__ v, const float* __restrict__ t,
    float* __restrict__ out)
{
    __shared__ float ssq[4];
    __shared__ float sdot[4];
    const int tid  = threadIdx.x;
    const int lane = tid & 63;
    const int wid  = tid >> 6;
    float sq = 0.f, dot = 0.f;
#pragma unroll
    for (int k = 0; k < 24; ++k) {
        float x = v[tid + 256 * k];
        float y = t[tid + 256 * k];
        sq  += x * x;
        dot += x * y;
    }
    sq  = wave_reduce(sq);
    dot = wave_reduce(dot);
    if (lane == 0) { ssq[wid] = sq; sdot[wid] = dot; }
    __syncthreads();
    if (tid == 0) {
        const float sqt  = ssq[0] + ssq[1] + ssq[2] + ssq[3];
        const float dott = sdot[0] + sdot[1] + sdot[2] + sdot[3];
        out[0] = 3.0f * dott * rsqrtf(sqt);
    }
}

extern "C" void kernel_launch(void* const* d_in, const int* in_sizes, int n_in,
                              void* d_out, int out_size, void* d_ws, size_t ws_size,
                              hipStream_t stream)
{
    const float* conv = (const float*)d_in[0];   // [2048,2048,3,3] fp32
    const float* u_in = (const float*)d_in[1];   // [1,6144] fp32, unit norm
    float* out = (float*)d_out;
    float* ws  = (float*)d_ws;

    // ws layout (floats):
    //   Wh (fp16 6144x6144)  = 18,874,368 floats
    //   v_vec[6144] | u_vec[6144] | t_vec[6144] | partials[128*6144]
    const size_t WH_FLOATS = (size_t)RC * RC / 2;
    const size_t needed = (WH_FLOATS + 3 * RC + (size_t)RGROUPS * RC) * sizeof(float);
    if (ws_size < needed) return;

    __half* Wh      = (__half*)ws;
    float* v_vec    = ws + WH_FLOATS;
    float* u_vec    = v_vec + RC;
    float* t_vec    = u_vec + RC;
    float* partials = t_vec + RC;

    // one-time fp32 -> permuted fp16
    convert_kernel<<<(RC * (RC / 8) / 256) / 1, 256, 0, stream>>>(conv, Wh);  // 18432 blocks

    for (int i = 0; i < 10; ++i) {
        vstep_h_kernel<<<RC / 16, 256, 0, stream>>>(Wh, (i == 0) ? u_in : u_vec, v_vec);
        ustep_h_kernel<<<3 * RGROUPS, 256, 0, stream>>>(Wh, v_vec, partials);
        ureduce_kernel<<<RC / 256, 256, 0, stream>>>(partials, u_vec);
    }
    // final sigma in full fp32 from original data
    vstep_kernel<<<OC_N, 256, 0, stream>>>(conv, u_vec, t_vec);
    final_kernel<<<1, 256, 0, stream>>>(v_vec, t_vec, out);
}

// Round 3
// 540.606 us; speedup vs baseline: 1.6926x; 1.0845x over previous
//
#include <hip/hip_runtime.h>
#include <hip/hip_bf16.h>
#include <hip/hip_fp16.h>

#define OC_N     2048
#define IC_N     2048
#define RC       6144      // rows = OC_N*3, cols = IC_N*3
#define OCSTRIDE 18432     // IC_N*9 floats per oc slice
#define RGROUPS  256       // ustep row-groups (24 rows each)
#define UNSCALE  0.0000152587890625f   // 2^-16 cancels the fp8 256x encode scale per iter

typedef float v2f __attribute__((ext_vector_type(2)));

__device__ __forceinline__ float wave_reduce(float x) {
#pragma unroll
    for (int off = 32; off > 0; off >>= 1) x += __shfl_down(x, off, 64);
    return x;
}

// ---------------------------------------------------------------------------
// Wq[r][c] = fp8_e4m3(256 * conv[oc][ic][hh][ww]), r=oc*3+hh, c=ic*3+ww.
// Thread writes 8 consecutive fp8 (8B store, coalesced). 18432 blocks.
__global__ __launch_bounds__(256) void convert_q_kernel(
    const float* __restrict__ conv, unsigned char* __restrict__ Wq)
{
    const int t  = blockIdx.x * 256 + threadIdx.x;
    const int o8 = t * 8;                       // < 2^26, fits int
    const int r  = o8 / RC;
    const int c0 = o8 % RC;
    const int oc = r / 3, hh = r % 3;
    const float* base = conv + (size_t)oc * OCSTRIDE + hh * 3;
    float f[8];
#pragma unroll
    for (int e = 0; e < 8; ++e) {
        const int c  = c0 + e;
        const int ic = c / 3, ww = c - 3 * ic;
        f[e] = base[ic * 9 + ww] * 256.0f;
    }
    int lo = __builtin_amdgcn_cvt_pk_fp8_f32(f[0], f[1], 0, false);
    lo     = __builtin_amdgcn_cvt_pk_fp8_f32(f[2], f[3], lo, true);
    int hi = __builtin_amdgcn_cvt_pk_fp8_f32(f[4], f[5], 0, false);
    hi     = __builtin_amdgcn_cvt_pk_fp8_f32(f[6], f[7], hi, true);
    *reinterpret_cast<uint2*>(Wq + o8) = make_uint2((unsigned)lo, (unsigned)hi);
}

// ---------------------------------------------------------------------------
// v_out[r] = sum_c Wq[r][c] * u[c]        (NO normalization — scale-free)
// 768 blocks x 256 thr (3/CU exact). Block = 8 rows, wave = 2 rows.
__global__ __launch_bounds__(256) void vstep_q_kernel(
    const unsigned char* __restrict__ Wq, const float* __restrict__ u,
    float* __restrict__ v_out)
{
    __shared__ float u_lds[RC];
    const int tid = threadIdx.x, lane = tid & 63, wid = tid >> 6;

    const float4* u4  = reinterpret_cast<const float4*>(u);
    float4*       ul4 = reinterpret_cast<float4*>(u_lds);
#pragma unroll
    for (int k = 0; k < 6; ++k) ul4[tid + 256 * k] = u4[tid + 256 * k];
    __syncthreads();

    const int rbase = blockIdx.x * 8 + wid * 2;
    const unsigned char* w0 = Wq + (size_t)rbase * RC;
    float acc0 = 0.f, acc1 = 0.f;
#pragma unroll
    for (int it = 0; it < 12; ++it) {
        const int c = it * 512 + lane * 8;        // 8B/lane, wave-contiguous
        const float4 ua = *reinterpret_cast<const float4*>(u_lds + c);
        const float4 ub = *reinterpret_cast<const float4*>(u_lds + c + 4);
        const uint2 wA = *reinterpret_cast<const uint2*>(w0 + c);
        const uint2 wB = *reinterpret_cast<const uint2*>(w0 + RC + c);
        {
            v2f f01 = __builtin_amdgcn_cvt_pk_f32_fp8(wA.x, false);
            v2f f23 = __builtin_amdgcn_cvt_pk_f32_fp8(wA.x, true);
            v2f f45 = __builtin_amdgcn_cvt_pk_f32_fp8(wA.y, false);
            v2f f67 = __builtin_amdgcn_cvt_pk_f32_fp8(wA.y, true);
            acc0 += f01.x*ua.x + f01.y*ua.y + f23.x*ua.z + f23.y*ua.w
                  + f45.x*ub.x + f45.y*ub.y + f67.x*ub.z + f67.y*ub.w;
        }
        {
            v2f f01 = __builtin_amdgcn_cvt_pk_f32_fp8(wB.x, false);
            v2f f23 = __builtin_amdgcn_cvt_pk_f32_fp8(wB.x, true);
            v2f f45 = __builtin_amdgcn_cvt_pk_f32_fp8(wB.y, false);
            v2f f67 = __builtin_amdgcn_cvt_pk_f32_fp8(wB.y, true);
            acc1 += f01.x*ua.x + f01.y*ua.y + f23.x*ua.z + f23.y*ua.w
                  + f45.x*ub.x + f45.y*ub.y + f67.x*ub.z + f67.y*ub.w;
        }
    }
    acc0 = wave_reduce(acc0);
    acc1 = wave_reduce(acc1);
    if (lane == 0) { v_out[rbase] = acc0; v_out[rbase + 1] = acc1; }
}

// ---------------------------------------------------------------------------
// partials[rg][c] = sum_{24 rows of rg} Wq[r][c] * v[r]   (no normalization)
// 768 blocks = 3 col-groups x 256 row-groups. Thread owns 8 consecutive cols.
__global__ __launch_bounds__(256) void ustep_q_kernel(
    const unsigned char* __restrict__ Wq, const float* __restrict__ v,
    float* __restrict__ partials)
{
    __shared__ float v_lds[24];
    const int tid = threadIdx.x;
    const int cg  = blockIdx.x % 3;
    const int rg  = blockIdx.x / 3;
    if (tid < 24) v_lds[tid] = v[rg * 24 + tid];
    __syncthreads();

    const int c0 = cg * 2048 + tid * 8;
    float acc[8];
#pragma unroll
    for (int e = 0; e < 8; ++e) acc[e] = 0.f;
    const unsigned char* wp = Wq + (size_t)(rg * 24) * RC + c0;
#pragma unroll 6
    for (int rr = 0; rr < 24; ++rr) {
        const uint2 w = *reinterpret_cast<const uint2*>(wp);
        wp += RC;
        const float vv = v_lds[rr];
        v2f f01 = __builtin_amdgcn_cvt_pk_f32_fp8(w.x, false);
        v2f f23 = __builtin_amdgcn_cvt_pk_f32_fp8(w.x, true);
        v2f f45 = __builtin_amdgcn_cvt_pk_f32_fp8(w.y, false);
        v2f f67 = __builtin_amdgcn_cvt_pk_f32_fp8(w.y, true);
        acc[0] += f01.x * vv; acc[1] += f01.y * vv;
        acc[2] += f23.x * vv; acc[3] += f23.y * vv;
        acc[4] += f45.x * vv; acc[5] += f45.y * vv;
        acc[6] += f67.x * vv; acc[7] += f67.y * vv;
    }
    float* po = partials + (size_t)rg * RC + c0;
    *reinterpret_cast<float4*>(po)     = make_float4(acc[0], acc[1], acc[2], acc[3]);
    *reinterpret_cast<float4*>(po + 4) = make_float4(acc[4], acc[5], acc[6], acc[7]);
}

// u_out[s] = 2^-16 * sum_rg partials[rg][s]   (96 blocks x 64 thr)
__global__ __launch_bounds__(64) void ureduce_kernel(
    const float* __restrict__ partials, float* __restrict__ u_out)
{
    const int s = blockIdx.x * 64 + threadIdx.x;
    float sum = 0.f;
#pragma unroll 8
    for (int b = 0; b < RGROUPS; ++b) sum += partials[(size_t)b * RC + s];
    u_out[s] = sum * UNSCALE;
}

// ---------------------------------------------------------------------------
// Final fp32 pass on ORIGINAL conv: t = W * (u/||u||). One block per oc.
__global__ __launch_bounds__(256) void vstep_kernel(
    const float* __restrict__ conv, const float* __restrict__ u,
    float* __restrict__ v_out)
{
    __shared__ float u_lds[RC];
    __shared__ float sred[8];
    __shared__ float sred3[12];
    __shared__ float sbcast;

    const int tid  = threadIdx.x;
    const int oc   = blockIdx.x;
    const int lane = tid & 63;
    const int wid  = tid >> 6;

    float sq = 0.f;
    const float4* u4  = reinterpret_cast<const float4*>(u);
    float4*       ul4 = reinterpret_cast<float4*>(u_lds);
#pragma unroll
    for (int k = 0; k < 6; ++k) {
        float4 q = u4[tid + 256 * k];
        ul4[tid + 256 * k] = q;
        sq += q.x * q.x + q.y * q.y + q.z * q.z + q.w * q.w;
    }
    float wsum = wave_reduce(sq);
    if (lane == 0) sred[wid] = wsum;
    __syncthreads();
    if (tid == 0) sbcast = rsqrtf(sred[0] + sred[1] + sred[2] + sred[3]);
    __syncthreads();
    const float scale = sbcast;

    float acc0 = 0.f, acc1 = 0.f, acc2 = 0.f;
    const float* base = conv + (size_t)oc * OCSTRIDE;
#pragma unroll
    for (int gi = 0; gi < 2; ++gi) {
        const int g = tid + 256 * gi;
        const float4* p4  = reinterpret_cast<const float4*>(base + g * 36);
        const float4* q12 = reinterpret_cast<const float4*>(u_lds + 12 * g);
        float uv[12];
#pragma unroll
        for (int k = 0; k < 3; ++k) {
            float4 q = q12[k];
            uv[4 * k] = q.x; uv[4 * k + 1] = q.y; uv[4 * k + 2] = q.z; uv[4 * k + 3] = q.w;
        }
#pragma unroll
        for (int j = 0; j < 9; ++j) {
            float4 q = p4[j];
            float el[4] = {q.x, q.y, q.z, q.w};
#pragma unroll
            for (int e = 0; e < 4; ++e) {
                const int m   = 4 * j + e;
                const int icl = m / 9;
                const int rem = m - 9 * icl;
                const int hh  = rem / 3;
                const int ww  = rem - 3 * hh;
                const float pv = el[e] * uv[icl * 3 + ww];
                if (hh == 0) acc0 += pv;
                else if (hh == 1) acc1 += pv;
                else acc2 += pv;
            }
        }
    }
    acc0 = wave_reduce(acc0);
    acc1 = wave_reduce(acc1);
    acc2 = wave_reduce(acc2);
    if (lane == 0) { sred3[wid] = acc0; sred3[4 + wid] = acc1; sred3[8 + wid] = acc2; }
    __syncthreads();
    if (tid < 3) {
        const float s = sred3[tid * 4 + 0] + sred3[tid * 4 + 1] +
                        sred3[tid * 4 + 2] + sred3[tid * 4 + 3];
        v_out[oc * 3 + tid] = scale * s;
    }
}

// out = 3 * dot(v,t) / ||v||   (v unnormalized iterate, t = W u_hat)
__global__ __launch_bounds__(256) void final_kernel(
    const float* __restrict__ v, const float* __restrict__ t,
    float* __restrict__ out)
{
    __shared__ float ssq[4];
    __shared__ float sdot[4];
    const int tid  = threadIdx.x;
    const int lane = tid & 63;
    const int wid  = tid >> 6;
    float sq = 0.f, dot = 0.f;
#pragma unroll
    for (int k = 0; k < 24; ++k) {
        float x = v[tid + 256 * k];
        float y = t[tid + 256 * k];
        sq  += x * x;
        dot += x * y;
    }
    sq  = wave_reduce(sq);
    dot = wave_reduce(dot);
    if (lane == 0) { ssq[wid] = sq; sdot[wid] = dot; }
    __syncthreads();
    if (tid == 0) {
        const float sqt  = ssq[0] + ssq[1] + ssq[2] + ssq[3];
        const float dott = sdot[0] + sdot[1] + sdot[2] + sdot[3];
        out[0] = 3.0f * dott * rsqrtf(sqt);
    }
}

extern "C" void kernel_launch(void* const* d_in, const int* in_sizes, int n_in,
                              void* d_out, int out_size, void* d_ws, size_t ws_size,
                              hipStream_t stream)
{
    const float* conv = (const float*)d_in[0];   // [2048,2048,3,3] fp32
    const float* u_in = (const float*)d_in[1];   // [1,6144] fp32, unit norm
    float* out = (float*)d_out;

    // ws layout: Wq fp8[6144*6144] | v_vec[6144] | u_vec[6144] | t_vec[6144]
    //            | partials[256*6144] floats
    const size_t WQ_BYTES = (size_t)RC * RC;                     // 37.75 MB
    const size_t needed = WQ_BYTES +
        ((size_t)3 * RC + (size_t)RGROUPS * RC) * sizeof(float);
    if (ws_size < needed) return;

    unsigned char* Wq = (unsigned char*)d_ws;
    float* v_vec    = (float*)(Wq + WQ_BYTES);
    float* u_vec    = v_vec + RC;
    float* t_vec    = u_vec + RC;
    float* partials = t_vec + RC;

    convert_q_kernel<<<RC * RC / 8 / 256, 256, 0, stream>>>(conv, Wq);

    for (int i = 0; i < 10; ++i) {
        vstep_q_kernel<<<RC / 8, 256, 0, stream>>>(Wq, (i == 0) ? u_in : u_vec, v_vec);
        ustep_q_kernel<<<3 * RGROUPS, 256, 0, stream>>>(Wq, v_vec, partials);
        ureduce_kernel<<<RC / 64, 64, 0, stream>>>(partials, u_vec);
    }
    // sigma in full fp32 from original data
    vstep_kernel<<<OC_N, 256, 0, stream>>>(conv, u_vec, t_vec);
    final_kernel<<<1, 256, 0, stream>>>(v_vec, t_vec, out);
}